// Round 2
// baseline (436.804 us; speedup 1.0000x reference)
//
#include <hip/hip_runtime.h>
#include <math.h>

#define FDIM 256
#define NGRAPH 128
#define NCLASS 10

typedef short short8 __attribute__((ext_vector_type(8)));
typedef float floatx4 __attribute__((ext_vector_type(4)));

// fp32 <-> bf16 helpers (RNE)
static __device__ __forceinline__ unsigned short f2bf(float f) {
    unsigned u = __float_as_uint(f);
    u += 0x7FFF + ((u >> 16) & 1);
    return (unsigned short)(u >> 16);
}
static __device__ __forceinline__ float bflo(unsigned u) { return __uint_as_float(u << 16); }
static __device__ __forceinline__ float bfhi(unsigned u) { return __uint_as_float(u & 0xFFFF0000u); }

// ---------------- prep: count+slot | packw x3 | zero g (one dispatch) ----------------
// slot is 16-bit (max in-degree ~50 << 65536)

__global__ __launch_bounds__(256) void prep_kernel(const int* __restrict__ dst,
                                                   int* __restrict__ cnt,
                                                   unsigned short* __restrict__ slot,
                                                   int E, int nCnt,
                                                   const float* __restrict__ W0,
                                                   const float* __restrict__ W1,
                                                   const float* __restrict__ W2,
                                                   unsigned short* __restrict__ Bp0,
                                                   unsigned short* __restrict__ Bp1,
                                                   unsigned short* __restrict__ Bp2,
                                                   float4* __restrict__ g4) {
    const int b = blockIdx.x;
    const int t = threadIdx.x;
    if (b < nCnt) {
        int e = b * 256 + t;
        if (e < E) slot[e] = (unsigned short)atomicAdd(&cnt[dst[e]], 1);
        return;
    }
    const int b2 = b - nCnt;
    if (b2 >= 96) {
        g4[(size_t)(b2 - 96) * 256 + t] = (float4){0.f, 0.f, 0.f, 0.f};
        return;
    }
    const float* W = (b2 < 32) ? W0 : (b2 < 64) ? W1 : W2;
    unsigned short* Bp = (b2 < 32) ? Bp0 : (b2 < 64) ? Bp1 : Bp2;
    int idx = (b2 & 31) * 256 + t;   // [0, 8192)
    int kstep = idx >> 10;
    int ntile = (idx >> 6) & 15;
    int lane  = idx & 63;
    int col   = ntile * 16 + (lane & 15);
    int krow  = kstep * 32 + (lane >> 4) * 8;
    unsigned short o[8];
#pragma unroll
    for (int j = 0; j < 8; j++) o[j] = f2bf(W[(size_t)(krow + j) * FDIM + col]);
    *(uint4*)(Bp + (size_t)idx * 8) = *(uint4*)o;
}

// ---------------- CSR scan (two dispatches), segments PADDED to multiple of 8 ----------------

__global__ __launch_bounds__(256) void csr_bsum(const int* __restrict__ cnt,
                                                int* __restrict__ bsum, int N) {
    __shared__ int red[256];
    const int t = threadIdx.x;
    const int base = blockIdx.x * 1024 + t * 4;
    int s = 0;
#pragma unroll
    for (int i = 0; i < 4; i++)
        if (base + i < N) s += (cnt[base + i] + 7) & ~7;   // padded counts
    red[t] = s;
    __syncthreads();
    for (int off = 128; off > 0; off >>= 1) {
        if (t < off) red[t] += red[t + off];
        __syncthreads();
    }
    if (t == 0) bsum[blockIdx.x] = red[0];
}

// scan2 with inlined block-offset (each block reduces bsum[0..bid))
__global__ __launch_bounds__(256) void csr_scan2(const int* __restrict__ cnt,
                                                 const int* __restrict__ bsum,
                                                 int* __restrict__ rowptr,
                                                 float* __restrict__ dinv, int N) {
    __shared__ int redo[256];
    __shared__ int tsum[256];
    const int t = threadIdx.x;
    const int bid = blockIdx.x;

    int pre = 0;
    for (int i = t; i < bid; i += 256) pre += bsum[i];
    redo[t] = pre;
    __syncthreads();
    for (int off = 128; off > 0; off >>= 1) {
        if (t < off) redo[t] += redo[t + off];
        __syncthreads();
    }
    const int blockoff = redo[0];
    __syncthreads();

    const int base = bid * 1024 + t * 4;
    int c[4], pc[4];
    int s = 0;
#pragma unroll
    for (int i = 0; i < 4; i++) {
        c[i] = (base + i < N) ? cnt[base + i] : 0;
        pc[i] = (c[i] + 7) & ~7;                 // padded
        s += pc[i];
    }
    tsum[t] = s;
    __syncthreads();
    for (int off = 1; off < 256; off <<= 1) {
        int v = (t >= off) ? tsum[t - off] : 0;
        __syncthreads();
        tsum[t] += v;
        __syncthreads();
    }
    int run = blockoff + ((t == 0) ? 0 : tsum[t - 1]);
#pragma unroll
    for (int i = 0; i < 4; i++) {
        int idx = base + i;
        if (idx < N) {
            rowptr[idx] = run;
            dinv[idx] = rsqrtf((float)c[i] + 1.0f);   // +1 = self loop (real count)
            run += pc[i];
            if (idx == N - 1) rowptr[N] = run;        // padded total
        }
    }
}

// ---------------- GEMM tile body: 64 rows/block, wave w owns cols [w*64, w*64+64) ----------------
// B slice register-resident (32 x short8 = 128 VGPR, loaded ONCE per block);
// A streamed 4 m-tiles x 8 ksteps; acc live only per m-tile (4 floatx4).

template<int AFP32>
static __device__ __forceinline__ void gemm_tile64(const void* __restrict__ A,
                                                   const unsigned short* __restrict__ Bp,
                                                   unsigned short* __restrict__ C,
                                                   int M, int tile) {
    const int wave = threadIdx.x >> 6;
    const int lane = threadIdx.x & 63;
    const int quad = lane >> 4;
    const int m    = lane & 15;
    const int row0 = tile * 64;

    short8 breg[8][4];
#pragma unroll
    for (int ks = 0; ks < 8; ks++)
#pragma unroll
        for (int j = 0; j < 4; j++)
            breg[ks][j] = *(const short8*)((const short*)Bp +
                            ((size_t)((ks * 16 + wave * 4 + j) * 64 + lane) * 8));

#pragma unroll
    for (int mt = 0; mt < 4; mt++) {
        const int r0 = min(row0 + mt * 16 + m, M - 1);   // clamp (A unpadded)
        floatx4 acc[4];
#pragma unroll
        for (int j = 0; j < 4; j++) acc[j] = (floatx4){0.f, 0.f, 0.f, 0.f};
#pragma unroll
        for (int ks = 0; ks < 8; ks++) {
            short8 a;
            if (AFP32) {
                const float* ar = (const float*)A + (size_t)r0 * FDIM + ks * 32 + quad * 8;
                float4 p0 = *(const float4*)ar;
                float4 p1 = *(const float4*)(ar + 4);
                a[0] = (short)f2bf(p0.x); a[1] = (short)f2bf(p0.y);
                a[2] = (short)f2bf(p0.z); a[3] = (short)f2bf(p0.w);
                a[4] = (short)f2bf(p1.x); a[5] = (short)f2bf(p1.y);
                a[6] = (short)f2bf(p1.z); a[7] = (short)f2bf(p1.w);
            } else {
                a = *(const short8*)((const short*)A + (size_t)r0 * FDIM + ks * 32 + quad * 8);
            }
#pragma unroll
            for (int j = 0; j < 4; j++)
                acc[j] = __builtin_amdgcn_mfma_f32_16x16x32_bf16(a, breg[ks][j], acc[j], 0, 0, 0);
        }
#pragma unroll
        for (int j = 0; j < 4; j++) {
            int col = (wave * 4 + j) * 16 + m;
#pragma unroll
            for (int r = 0; r < 4; r++) {
                int row = row0 + mt * 16 + quad * 4 + r;
                if (row < M) C[(size_t)row * FDIM + col] = f2bf(acc[j][r]);
            }
        }
    }
}

// combo: blocks [0,ng) = gemm0 tiles (fp32 A); blocks [ng, ...) = CSR fill (srcs + norm)
__global__ __launch_bounds__(256, 2) void gemm0_fill_kernel(const float* __restrict__ x,
                                                            const unsigned short* __restrict__ Bp0,
                                                            unsigned short* __restrict__ H,
                                                            int M, int ng,
                                                            const int* __restrict__ src,
                                                            const int* __restrict__ dst,
                                                            const int* __restrict__ rowptr,
                                                            const unsigned short* __restrict__ slot,
                                                            unsigned short* __restrict__ srcs,
                                                            float* __restrict__ normv,
                                                            const float* __restrict__ dinv, int E) {
    if ((int)blockIdx.x < ng) {
        gemm_tile64<1>(x, Bp0, H, M, blockIdx.x);
        return;
    }
    int e = (blockIdx.x - ng) * 256 + threadIdx.x;
    if (e < E) {
        int s = src[e], d = dst[e];
        int r = rowptr[d] + (int)slot[e];
        srcs[r] = (unsigned short)s;
        normv[r] = dinv[s] * dinv[d];
    }
}

// bf16 GEMM: standalone dispatch
__global__ __launch_bounds__(256, 2) void mfma_gemm(const unsigned short* __restrict__ A,
                                                    const unsigned short* __restrict__ Bp,
                                                    unsigned short* __restrict__ C, int M) {
    gemm_tile64<0>(A, Bp, C, M, blockIdx.x);
}

// ---------------- gather core v2: one node per 64-lane wave, norm precomputed ----------------
// Segments are multiples of 8 (zero-padded: srcs=0, norm=0 => contributes 0).
// Per iteration: 1x uint4 (8 srcs) + 2x float4 (8 norms) + 8x uint2 row loads in flight.

static __device__ __forceinline__ void gather_node64(const unsigned short* __restrict__ h,
                                                     const int* __restrict__ rowptr,
                                                     const unsigned short* __restrict__ srcs,
                                                     const float* __restrict__ normv,
                                                     const float* __restrict__ dinv,
                                                     const float* __restrict__ bias,
                                                     int node, int lane, float* acc) {
    const float di = dinv[node];
    const float dii = di * di;
    uint2 sv = *(const uint2*)(h + (size_t)node * FDIM + lane * 4);
    float4 b = *(const float4*)(bias + lane * 4);
    acc[0] = dii * bflo(sv.x) + b.x;
    acc[1] = dii * bfhi(sv.x) + b.y;
    acc[2] = dii * bflo(sv.y) + b.z;
    acc[3] = dii * bfhi(sv.y) + b.w;

    const int beg = rowptr[node];
    const int end = rowptr[node + 1];
    for (int p = beg; p < end; p += 8) {
        uint4 s8 = *(const uint4*)(srcs + p);          // 8 x u16, 16B aligned
        float4 n0 = *(const float4*)(normv + p);
        float4 n1 = *(const float4*)(normv + p + 4);
        const unsigned short* sp = (const unsigned short*)&s8;
        uint2 v[8];
#pragma unroll
        for (int i = 0; i < 8; i++)
            v[i] = *(const uint2*)(h + (size_t)sp[i] * FDIM + lane * 4);
        float nm[8] = {n0.x, n0.y, n0.z, n0.w, n1.x, n1.y, n1.z, n1.w};
#pragma unroll
        for (int i = 0; i < 8; i++) {
            acc[0] += nm[i] * bflo(v[i].x);
            acc[1] += nm[i] * bfhi(v[i].x);
            acc[2] += nm[i] * bflo(v[i].y);
            acc[3] += nm[i] * bfhi(v[i].y);
        }
    }
#pragma unroll
    for (int i = 0; i < 4; i++) acc[i] = fmaxf(acc[i], 0.0f);
}

__global__ __launch_bounds__(256) void gather_kernel(const unsigned short* __restrict__ h,
                                                     const int* __restrict__ rowptr,
                                                     const unsigned short* __restrict__ srcs,
                                                     const float* __restrict__ normv,
                                                     const float* __restrict__ dinv,
                                                     const float* __restrict__ bias,
                                                     unsigned short* __restrict__ out, int N) {
    int node = blockIdx.x * 4 + (threadIdx.x >> 6);
    node = __builtin_amdgcn_readfirstlane(node);       // wave-uniform -> scalar loads
    const int lane = threadIdx.x & 63;
    if (node >= N) return;
    float acc[4];
    gather_node64(h, rowptr, srcs, normv, dinv, bias, node, lane, acc);
    unsigned short o[4];
#pragma unroll
    for (int i = 0; i < 4; i++) o[i] = f2bf(acc[i]);
    *(uint2*)(out + (size_t)node * FDIM + lane * 4) = *(uint2*)o;
}

// last layer: gather + pool fused
__global__ __launch_bounds__(256) void gather_pool_kernel(const unsigned short* __restrict__ h,
                                                          const int* __restrict__ rowptr,
                                                          const unsigned short* __restrict__ srcs,
                                                          const float* __restrict__ normv,
                                                          const float* __restrict__ dinv,
                                                          const float* __restrict__ bias,
                                                          const int* __restrict__ batch,
                                                          float* __restrict__ g, int N) {
    __shared__ float red[4][FDIM];   // 4 KB
    __shared__ int bid[4];
    const int hw   = threadIdx.x >> 6;
    const int lane = threadIdx.x & 63;
    int node = blockIdx.x * 4 + hw;
    node = __builtin_amdgcn_readfirstlane(node);

    float acc[4] = {0.f, 0.f, 0.f, 0.f};
    if (node < N) gather_node64(h, rowptr, srcs, normv, dinv, bias, node, lane, acc);
#pragma unroll
    for (int i = 0; i < 4; i++) red[hw][lane * 4 + i] = acc[i];
    if (lane == 0) bid[hw] = (node < N) ? batch[node] : -1;
    __syncthreads();

    const int f = threadIdx.x;
    int cur = -1;
    float run = 0.0f;
    for (int i = 0; i < 4; i++) {
        int b = bid[i];
        if (b < 0) break;
        if (b != cur) {
            if (cur >= 0) atomicAdd(&g[(size_t)cur * FDIM + f], run);
            cur = b;
            run = 0.0f;
        }
        run += red[i][f];
    }
    if (cur >= 0) atomicAdd(&g[(size_t)cur * FDIM + f], run);
}

// ---------------- fused FC head ----------------

__global__ __launch_bounds__(256) void fc_head_kernel(const float* __restrict__ g,
                                                      const float* __restrict__ fc1W,
                                                      const float* __restrict__ fc1b,
                                                      const float* __restrict__ fc2W,
                                                      const float* __restrict__ fc2b,
                                                      float* __restrict__ out) {
    __shared__ float gs[FDIM];
    __shared__ float part[4][FDIM];
    __shared__ float hs[FDIM];
    __shared__ float p2[256];
    __shared__ float logits[NCLASS];
    const int r = blockIdx.x;
    const int t = threadIdx.x;
    const int w = t >> 6;
    const int l = t & 63;

    gs[t] = g[(size_t)r * FDIM + t];
    __syncthreads();

    float a[4] = {0.f, 0.f, 0.f, 0.f};
    for (int kk = 0; kk < 64; kk++) {
        int k = w * 64 + kk;
        float gv = gs[k];
#pragma unroll
        for (int j = 0; j < 4; j++) a[j] += gv * fc1W[(size_t)k * FDIM + j * 64 + l];
    }
#pragma unroll
    for (int j = 0; j < 4; j++) part[w][j * 64 + l] = a[j];
    __syncthreads();

    float s1 = part[0][t] + part[1][t] + part[2][t] + part[3][t] + fc1b[t];
    hs[t] = fmaxf(s1, 0.0f);
    __syncthreads();

    float a2 = 0.0f;
    const int c = t & 15;
    if (c < NCLASS) {
        int k0 = (t >> 4) * 16;
        for (int kk = 0; kk < 16; kk++)
            a2 += hs[k0 + kk] * fc2W[(size_t)(k0 + kk) * NCLASS + c];
    }
    p2[t] = a2;
    __syncthreads();

    if (t < NCLASS) {
        float s2 = fc2b[t];
        for (int seg = 0; seg < 16; seg++) s2 += p2[seg * 16 + t];
        logits[t] = s2;
    }
    __syncthreads();

    if (t == 0) {
        float mx = logits[0];
        for (int cc = 1; cc < NCLASS; cc++) mx = fmaxf(mx, logits[cc]);
        float ssum = 0.0f;
        for (int cc = 0; cc < NCLASS; cc++) ssum += expf(logits[cc] - mx);
        float lse = mx + logf(ssum);
        for (int cc = 0; cc < NCLASS; cc++) out[(size_t)r * NCLASS + cc] = logits[cc] - lse;
    }
}

// ---------------- launcher ----------------

extern "C" void kernel_launch(void* const* d_in, const int* in_sizes, int n_in,
                              void* d_out, int out_size, void* d_ws, size_t ws_size,
                              hipStream_t stream) {
    const float* x     = (const float*)d_in[0];
    const int*   ei    = (const int*)d_in[1];
    const int*   batch = (const int*)d_in[2];
    const float* W0 = (const float*)d_in[3];  const float* b0 = (const float*)d_in[4];
    const float* W1 = (const float*)d_in[5];  const float* b1 = (const float*)d_in[6];
    const float* W2 = (const float*)d_in[7];  const float* b2 = (const float*)d_in[8];
    const float* fc1W = (const float*)d_in[9];  const float* fc1b = (const float*)d_in[10];
    const float* fc2W = (const float*)d_in[11]; const float* fc2b = (const float*)d_in[12];
    float* out = (float*)d_out;

    const int N = in_sizes[0] / FDIM;
    const int E = in_sizes[1] / 2;
    const int* src = ei;
    const int* dst = ei + E;
    const int Mpad = ((N + 63) / 64) * 64;
    const int nb   = (N + 1023) / 1024;
    const int nCnt = (E + 255) / 256;
    const int ng   = (N + 63) / 64;              // 64 rows per block
    const size_t Epad = (size_t)E + 8 * (size_t)N;   // upper bound on padded CSR length

    // workspace layout (16B-aligned chunks)
    char* p = (char*)d_ws;
    unsigned short* S  = (unsigned short*)p; p += (size_t)Mpad * FDIM * 2;  // node state
    unsigned short* H  = (unsigned short*)p; p += (size_t)Mpad * FDIM * 2;  // GEMM out
    unsigned short* Wp0 = (unsigned short*)p; p += (size_t)8192 * 8 * 2;
    unsigned short* Wp1 = (unsigned short*)p; p += (size_t)8192 * 8 * 2;
    unsigned short* Wp2 = (unsigned short*)p; p += (size_t)8192 * 8 * 2;
    float* dinv = (float*)p; p += (size_t)N * 4;
    int*   cnt  = (int*)p;   p += (size_t)N * 4;
    int*   rowptr = (int*)p; p += (size_t)(N + 4) * 4;
    int*   bsum = (int*)p;   p += (size_t)256 * 4;
    unsigned short* srcs = (unsigned short*)p; p += ((Epad * 2 + 15) & ~15ull);
    unsigned short* slot = (unsigned short*)p; p += (((size_t)E * 2 + 15) & ~15ull);
    float* normv = (float*)p; p += ((Epad * 4 + 15) & ~15ull);
    float* g    = (float*)p;

    // ---- CSR build + weight pack ----
    hipMemsetAsync(cnt, 0, (size_t)N * sizeof(int), stream);
    hipMemsetAsync(srcs, 0, Epad * 2, stream);       // pad entries -> node 0
    hipMemsetAsync(normv, 0, Epad * 4, stream);      // pad entries -> weight 0
    prep_kernel<<<nCnt + 128, 256, 0, stream>>>(dst, cnt, slot, E, nCnt,
                                                W0, W1, W2, Wp0, Wp1, Wp2, (float4*)g);
    csr_bsum<<<nb, 256, 0, stream>>>(cnt, bsum, N);
    csr_scan2<<<nb, 256, 0, stream>>>(cnt, bsum, rowptr, dinv, N);

    // ---- gemm0 (x@W0 -> H) + fill (srcs + norm), one dispatch ----
    gemm0_fill_kernel<<<ng + nCnt, 256, 0, stream>>>(x, Wp0, H, N, ng,
                                                     src, dst, rowptr, slot, srcs, normv, dinv, E);

    // ---- layers ----
    gather_kernel<<<(N + 3) / 4, 256, 0, stream>>>(H, rowptr, srcs, normv, dinv, b0, S, N);
    mfma_gemm<<<ng, 256, 0, stream>>>(S, Wp1, H, N);
    gather_kernel<<<(N + 3) / 4, 256, 0, stream>>>(H, rowptr, srcs, normv, dinv, b1, S, N);
    mfma_gemm<<<ng, 256, 0, stream>>>(S, Wp2, H, N);
    gather_pool_kernel<<<(N + 3) / 4, 256, 0, stream>>>(H, rowptr, srcs, normv, dinv, b2,
                                                        batch, g, N);
    fc_head_kernel<<<NGRAPH, 256, 0, stream>>>(g, fc1W, fc1b, fc2W, fc2b, out);
}

// Round 3
// 415.825 us; speedup vs baseline: 1.0505x; 1.0505x over previous
//
#include <hip/hip_runtime.h>
#include <math.h>

#define FDIM 256
#define NGRAPH 128
#define NCLASS 10

typedef short short8 __attribute__((ext_vector_type(8)));
typedef float floatx4 __attribute__((ext_vector_type(4)));

// fp32 <-> bf16 helpers (RNE)
static __device__ __forceinline__ unsigned short f2bf(float f) {
    unsigned u = __float_as_uint(f);
    u += 0x7FFF + ((u >> 16) & 1);
    return (unsigned short)(u >> 16);
}
static __device__ __forceinline__ float bflo(unsigned u) { return __uint_as_float(u << 16); }
static __device__ __forceinline__ float bfhi(unsigned u) { return __uint_as_float(u & 0xFFFF0000u); }

// ---------------- prep: count+slot | packw x3 | zero g | zero sentinel rows ----------------

__global__ __launch_bounds__(256) void prep_kernel(const int* __restrict__ dst,
                                                   int* __restrict__ cnt,
                                                   unsigned short* __restrict__ slot,
                                                   int E, int nCnt, int N,
                                                   const float* __restrict__ W0,
                                                   const float* __restrict__ W1,
                                                   const float* __restrict__ W2,
                                                   unsigned short* __restrict__ Bp0,
                                                   unsigned short* __restrict__ Bp1,
                                                   unsigned short* __restrict__ Bp2,
                                                   float4* __restrict__ g4,
                                                   unsigned short* __restrict__ Hrow,
                                                   unsigned short* __restrict__ Srow) {
    const int b = blockIdx.x;
    const int t = threadIdx.x;
    if (b < nCnt) {
        int e = b * 256 + t;
        if (e < E) slot[e] = (unsigned short)atomicAdd(&cnt[dst[e]], 1);
        return;
    }
    const int b2 = b - nCnt;
    if (b2 >= 128) {                      // zero sentinel row N of H and S
        Hrow[(size_t)N * FDIM + t] = 0;
        Srow[(size_t)N * FDIM + t] = 0;
        return;
    }
    if (b2 >= 96) {
        g4[(size_t)(b2 - 96) * 256 + t] = (float4){0.f, 0.f, 0.f, 0.f};
        return;
    }
    const float* W = (b2 < 32) ? W0 : (b2 < 64) ? W1 : W2;
    unsigned short* Bp = (b2 < 32) ? Bp0 : (b2 < 64) ? Bp1 : Bp2;
    int idx = (b2 & 31) * 256 + t;   // [0, 8192)
    int kstep = idx >> 10;
    int ntile = (idx >> 6) & 15;
    int lane  = idx & 63;
    int col   = ntile * 16 + (lane & 15);
    int krow  = kstep * 32 + (lane >> 4) * 8;
    unsigned short o[8];
#pragma unroll
    for (int j = 0; j < 8; j++) o[j] = f2bf(W[(size_t)(krow + j) * FDIM + col]);
    *(uint4*)(Bp + (size_t)idx * 8) = *(uint4*)o;
}

// ---------------- CSR scan (two dispatches), segments PADDED to multiple of 8 ----------------
// Pad entries get sentinel src = N (dinv[N]=0 => zero contribution).

__global__ __launch_bounds__(256) void csr_bsum(const int* __restrict__ cnt,
                                                int* __restrict__ bsum, int N) {
    __shared__ int red[256];
    const int t = threadIdx.x;
    const int base = blockIdx.x * 1024 + t * 4;
    int s = 0;
#pragma unroll
    for (int i = 0; i < 4; i++)
        if (base + i < N) s += (cnt[base + i] + 7) & ~7;   // padded counts
    red[t] = s;
    __syncthreads();
    for (int off = 128; off > 0; off >>= 1) {
        if (t < off) red[t] += red[t + off];
        __syncthreads();
    }
    if (t == 0) bsum[blockIdx.x] = red[0];
}

__global__ __launch_bounds__(256) void csr_scan2(const int* __restrict__ cnt,
                                                 const int* __restrict__ bsum,
                                                 int* __restrict__ rowptr,
                                                 float* __restrict__ dinv,
                                                 unsigned short* __restrict__ srcs, int N) {
    __shared__ int redo[256];
    __shared__ int tsum[256];
    const int t = threadIdx.x;
    const int bid = blockIdx.x;

    int pre = 0;
    for (int i = t; i < bid; i += 256) pre += bsum[i];
    redo[t] = pre;
    __syncthreads();
    for (int off = 128; off > 0; off >>= 1) {
        if (t < off) redo[t] += redo[t + off];
        __syncthreads();
    }
    const int blockoff = redo[0];
    __syncthreads();

    const int base = bid * 1024 + t * 4;
    int c[4], pc[4];
    int s = 0;
#pragma unroll
    for (int i = 0; i < 4; i++) {
        c[i] = (base + i < N) ? cnt[base + i] : 0;
        pc[i] = (c[i] + 7) & ~7;                 // padded
        s += pc[i];
    }
    tsum[t] = s;
    __syncthreads();
    for (int off = 1; off < 256; off <<= 1) {
        int v = (t >= off) ? tsum[t - off] : 0;
        __syncthreads();
        tsum[t] += v;
        __syncthreads();
    }
    int run = blockoff + ((t == 0) ? 0 : tsum[t - 1]);
    const unsigned short sent = (unsigned short)N;
#pragma unroll
    for (int i = 0; i < 4; i++) {
        int idx = base + i;
        if (idx < N) {
            rowptr[idx] = run;
            dinv[idx] = rsqrtf((float)c[i] + 1.0f);   // +1 = self loop (real count)
            for (int j = c[i]; j < pc[i]; j++) srcs[run + j] = sent;   // pad entries
            run += pc[i];
            if (idx == N - 1) rowptr[N] = run;        // padded total
        }
    }
    if (bid == 0 && t == 0) dinv[N] = 0.0f;           // sentinel weight
}

// ---------------- GEMM tile body: 64 rows/block, wave w owns cols [w*64, w*64+64) ----------------
// B slice register-resident (32 x short8 = 128 VGPR, loaded ONCE per block);
// A streamed 4 m-tiles x 8 ksteps; acc live only per m-tile (4 floatx4).

template<int AFP32>
static __device__ __forceinline__ void gemm_tile64(const void* __restrict__ A,
                                                   const unsigned short* __restrict__ Bp,
                                                   unsigned short* __restrict__ C,
                                                   int M, int tile) {
    const int wave = threadIdx.x >> 6;
    const int lane = threadIdx.x & 63;
    const int quad = lane >> 4;
    const int m    = lane & 15;
    const int row0 = tile * 64;

    short8 breg[8][4];
#pragma unroll
    for (int ks = 0; ks < 8; ks++)
#pragma unroll
        for (int j = 0; j < 4; j++)
            breg[ks][j] = *(const short8*)((const short*)Bp +
                            ((size_t)((ks * 16 + wave * 4 + j) * 64 + lane) * 8));

#pragma unroll
    for (int mt = 0; mt < 4; mt++) {
        const int r0 = min(row0 + mt * 16 + m, M - 1);   // clamp (A unpadded)
        floatx4 acc[4];
#pragma unroll
        for (int j = 0; j < 4; j++) acc[j] = (floatx4){0.f, 0.f, 0.f, 0.f};
#pragma unroll
        for (int ks = 0; ks < 8; ks++) {
            short8 a;
            if (AFP32) {
                const float* ar = (const float*)A + (size_t)r0 * FDIM + ks * 32 + quad * 8;
                float4 p0 = *(const float4*)ar;
                float4 p1 = *(const float4*)(ar + 4);
                a[0] = (short)f2bf(p0.x); a[1] = (short)f2bf(p0.y);
                a[2] = (short)f2bf(p0.z); a[3] = (short)f2bf(p0.w);
                a[4] = (short)f2bf(p1.x); a[5] = (short)f2bf(p1.y);
                a[6] = (short)f2bf(p1.z); a[7] = (short)f2bf(p1.w);
            } else {
                a = *(const short8*)((const short*)A + (size_t)r0 * FDIM + ks * 32 + quad * 8);
            }
#pragma unroll
            for (int j = 0; j < 4; j++)
                acc[j] = __builtin_amdgcn_mfma_f32_16x16x32_bf16(a, breg[ks][j], acc[j], 0, 0, 0);
        }
#pragma unroll
        for (int j = 0; j < 4; j++) {
            int col = (wave * 4 + j) * 16 + m;
#pragma unroll
            for (int r = 0; r < 4; r++) {
                int row = row0 + mt * 16 + quad * 4 + r;
                if (row < M) C[(size_t)row * FDIM + col] = f2bf(acc[j][r]);
            }
        }
    }
}

// combo: blocks [0,ng) = gemm0 tiles (fp32 A); blocks [ng, ...) = CSR fill (srcs only)
__global__ __launch_bounds__(256, 2) void gemm0_fill_kernel(const float* __restrict__ x,
                                                            const unsigned short* __restrict__ Bp0,
                                                            unsigned short* __restrict__ H,
                                                            int M, int ng,
                                                            const int* __restrict__ src,
                                                            const int* __restrict__ dst,
                                                            const int* __restrict__ rowptr,
                                                            const unsigned short* __restrict__ slot,
                                                            unsigned short* __restrict__ srcs, int E) {
    if ((int)blockIdx.x < ng) {
        gemm_tile64<1>(x, Bp0, H, M, blockIdx.x);
        return;
    }
    int e = (blockIdx.x - ng) * 256 + threadIdx.x;
    if (e < E) srcs[rowptr[dst[e]] + (int)slot[e]] = (unsigned short)src[e];
}

// bf16 GEMM: standalone dispatch
__global__ __launch_bounds__(256, 2) void mfma_gemm(const unsigned short* __restrict__ A,
                                                    const unsigned short* __restrict__ Bp,
                                                    unsigned short* __restrict__ C, int M) {
    gemm_tile64<0>(A, Bp, C, M, blockIdx.x);
}

// ---------------- gather core: one node per 64-lane wave ----------------
// Segments padded to x8; pad entries have src=N with dinv[N]=0 and zeroed row N.
// Per iteration: 1x uint4 (8 srcs, uniform) + 8 scalar dinv loads + 8 uint2 row loads in flight.

static __device__ __forceinline__ void gather_node64(const unsigned short* __restrict__ h,
                                                     const int* __restrict__ rowptr,
                                                     const unsigned short* __restrict__ srcs,
                                                     const float* __restrict__ dinv,
                                                     const float* __restrict__ bias,
                                                     int node, int lane, float* acc) {
    const float di = dinv[node];
    const float dii = di * di;
    uint2 sv = *(const uint2*)(h + (size_t)node * FDIM + lane * 4);
    float4 b = *(const float4*)(bias + lane * 4);
    acc[0] = dii * bflo(sv.x) + b.x;
    acc[1] = dii * bfhi(sv.x) + b.y;
    acc[2] = dii * bflo(sv.y) + b.z;
    acc[3] = dii * bfhi(sv.y) + b.w;

    const int beg = rowptr[node];
    const int end = rowptr[node + 1];
    for (int p = beg; p < end; p += 8) {
        uint4 s8 = *(const uint4*)(srcs + p);          // 8 x u16, wave-uniform
        const unsigned short* sp = (const unsigned short*)&s8;
        int si[8];
        float ds[8];
        uint2 v[8];
#pragma unroll
        for (int i = 0; i < 8; i++) {
            si[i] = __builtin_amdgcn_readfirstlane((int)sp[i]);   // scalarize
            ds[i] = dinv[si[i]];                                   // SMEM path
            v[i] = *(const uint2*)(h + (size_t)si[i] * FDIM + lane * 4);
        }
#pragma unroll
        for (int i = 0; i < 8; i++) {
            float nm = ds[i] * di;
            acc[0] += nm * bflo(v[i].x);
            acc[1] += nm * bfhi(v[i].x);
            acc[2] += nm * bflo(v[i].y);
            acc[3] += nm * bfhi(v[i].y);
        }
    }
#pragma unroll
    for (int i = 0; i < 4; i++) acc[i] = fmaxf(acc[i], 0.0f);
}

__global__ __launch_bounds__(256) void gather_kernel(const unsigned short* __restrict__ h,
                                                     const int* __restrict__ rowptr,
                                                     const unsigned short* __restrict__ srcs,
                                                     const float* __restrict__ dinv,
                                                     const float* __restrict__ bias,
                                                     unsigned short* __restrict__ out, int N) {
    int node = blockIdx.x * 4 + (threadIdx.x >> 6);
    node = __builtin_amdgcn_readfirstlane(node);       // wave-uniform -> scalar loads
    const int lane = threadIdx.x & 63;
    if (node >= N) return;
    float acc[4];
    gather_node64(h, rowptr, srcs, dinv, bias, node, lane, acc);
    unsigned short o[4];
#pragma unroll
    for (int i = 0; i < 4; i++) o[i] = f2bf(acc[i]);
    *(uint2*)(out + (size_t)node * FDIM + lane * 4) = *(uint2*)o;
}

// last layer: gather + pool fused
__global__ __launch_bounds__(256) void gather_pool_kernel(const unsigned short* __restrict__ h,
                                                          const int* __restrict__ rowptr,
                                                          const unsigned short* __restrict__ srcs,
                                                          const float* __restrict__ dinv,
                                                          const float* __restrict__ bias,
                                                          const int* __restrict__ batch,
                                                          float* __restrict__ g, int N) {
    __shared__ float red[4][FDIM];   // 4 KB
    __shared__ int bid[4];
    const int hw   = threadIdx.x >> 6;
    const int lane = threadIdx.x & 63;
    int node = blockIdx.x * 4 + hw;
    node = __builtin_amdgcn_readfirstlane(node);

    float acc[4] = {0.f, 0.f, 0.f, 0.f};
    if (node < N) gather_node64(h, rowptr, srcs, dinv, bias, node, lane, acc);
#pragma unroll
    for (int i = 0; i < 4; i++) red[hw][lane * 4 + i] = acc[i];
    if (lane == 0) bid[hw] = (node < N) ? batch[node] : -1;
    __syncthreads();

    const int f = threadIdx.x;
    int cur = -1;
    float run = 0.0f;
    for (int i = 0; i < 4; i++) {
        int b = bid[i];
        if (b < 0) break;
        if (b != cur) {
            if (cur >= 0) atomicAdd(&g[(size_t)cur * FDIM + f], run);
            cur = b;
            run = 0.0f;
        }
        run += red[i][f];
    }
    if (cur >= 0) atomicAdd(&g[(size_t)cur * FDIM + f], run);
}

// ---------------- fused FC head ----------------

__global__ __launch_bounds__(256) void fc_head_kernel(const float* __restrict__ g,
                                                      const float* __restrict__ fc1W,
                                                      const float* __restrict__ fc1b,
                                                      const float* __restrict__ fc2W,
                                                      const float* __restrict__ fc2b,
                                                      float* __restrict__ out) {
    __shared__ float gs[FDIM];
    __shared__ float part[4][FDIM];
    __shared__ float hs[FDIM];
    __shared__ float p2[256];
    __shared__ float logits[NCLASS];
    const int r = blockIdx.x;
    const int t = threadIdx.x;
    const int w = t >> 6;
    const int l = t & 63;

    gs[t] = g[(size_t)r * FDIM + t];
    __syncthreads();

    float a[4] = {0.f, 0.f, 0.f, 0.f};
    for (int kk = 0; kk < 64; kk++) {
        int k = w * 64 + kk;
        float gv = gs[k];
#pragma unroll
        for (int j = 0; j < 4; j++) a[j] += gv * fc1W[(size_t)k * FDIM + j * 64 + l];
    }
#pragma unroll
    for (int j = 0; j < 4; j++) part[w][j * 64 + l] = a[j];
    __syncthreads();

    float s1 = part[0][t] + part[1][t] + part[2][t] + part[3][t] + fc1b[t];
    hs[t] = fmaxf(s1, 0.0f);
    __syncthreads();

    float a2 = 0.0f;
    const int c = t & 15;
    if (c < NCLASS) {
        int k0 = (t >> 4) * 16;
        for (int kk = 0; kk < 16; kk++)
            a2 += hs[k0 + kk] * fc2W[(size_t)(k0 + kk) * NCLASS + c];
    }
    p2[t] = a2;
    __syncthreads();

    if (t < NCLASS) {
        float s2 = fc2b[t];
        for (int seg = 0; seg < 16; seg++) s2 += p2[seg * 16 + t];
        logits[t] = s2;
    }
    __syncthreads();

    if (t == 0) {
        float mx = logits[0];
        for (int cc = 1; cc < NCLASS; cc++) mx = fmaxf(mx, logits[cc]);
        float ssum = 0.0f;
        for (int cc = 0; cc < NCLASS; cc++) ssum += expf(logits[cc] - mx);
        float lse = mx + logf(ssum);
        for (int cc = 0; cc < NCLASS; cc++) out[(size_t)r * NCLASS + cc] = logits[cc] - lse;
    }
}

// ---------------- launcher ----------------

extern "C" void kernel_launch(void* const* d_in, const int* in_sizes, int n_in,
                              void* d_out, int out_size, void* d_ws, size_t ws_size,
                              hipStream_t stream) {
    const float* x     = (const float*)d_in[0];
    const int*   ei    = (const int*)d_in[1];
    const int*   batch = (const int*)d_in[2];
    const float* W0 = (const float*)d_in[3];  const float* b0 = (const float*)d_in[4];
    const float* W1 = (const float*)d_in[5];  const float* b1 = (const float*)d_in[6];
    const float* W2 = (const float*)d_in[7];  const float* b2 = (const float*)d_in[8];
    const float* fc1W = (const float*)d_in[9];  const float* fc1b = (const float*)d_in[10];
    const float* fc2W = (const float*)d_in[11]; const float* fc2b = (const float*)d_in[12];
    float* out = (float*)d_out;

    const int N = in_sizes[0] / FDIM;
    const int E = in_sizes[1] / 2;
    const int* src = ei;
    const int* dst = ei + E;
    const int Mpad = ((N + 63) / 64) * 64;
    const int nb   = (N + 1023) / 1024;
    const int nCnt = (E + 255) / 256;
    const int ng   = (N + 63) / 64;              // 64 rows per block
    const size_t Epad = (size_t)E + 8 * (size_t)N;   // upper bound on padded CSR length

    // workspace layout (16B-aligned chunks); +1 row on S/H for sentinel node N
    char* p = (char*)d_ws;
    unsigned short* S  = (unsigned short*)p; p += (size_t)(Mpad + 64) * FDIM * 2;  // node state
    unsigned short* H  = (unsigned short*)p; p += (size_t)(Mpad + 64) * FDIM * 2;  // GEMM out
    unsigned short* Wp0 = (unsigned short*)p; p += (size_t)8192 * 8 * 2;
    unsigned short* Wp1 = (unsigned short*)p; p += (size_t)8192 * 8 * 2;
    unsigned short* Wp2 = (unsigned short*)p; p += (size_t)8192 * 8 * 2;
    float* dinv = (float*)p; p += (((size_t)(N + 1) * 4 + 15) & ~15ull);
    int*   cnt  = (int*)p;   p += (size_t)N * 4;
    int*   rowptr = (int*)p; p += (size_t)(N + 4) * 4;
    int*   bsum = (int*)p;   p += (size_t)256 * 4;
    unsigned short* srcs = (unsigned short*)p; p += ((Epad * 2 + 15) & ~15ull);
    unsigned short* slot = (unsigned short*)p; p += (((size_t)E * 2 + 15) & ~15ull);
    float* g    = (float*)p;

    // ---- CSR build + weight pack ----
    hipMemsetAsync(cnt, 0, (size_t)N * sizeof(int), stream);
    prep_kernel<<<nCnt + 129, 256, 0, stream>>>(dst, cnt, slot, E, nCnt, N,
                                                W0, W1, W2, Wp0, Wp1, Wp2, (float4*)g, H, S);
    csr_bsum<<<nb, 256, 0, stream>>>(cnt, bsum, N);
    csr_scan2<<<nb, 256, 0, stream>>>(cnt, bsum, rowptr, dinv, srcs, N);

    // ---- gemm0 (x@W0 -> H) + fill (srcs), one dispatch ----
    gemm0_fill_kernel<<<ng + nCnt, 256, 0, stream>>>(x, Wp0, H, N, ng,
                                                     src, dst, rowptr, slot, srcs, E);

    // ---- layers ----
    gather_kernel<<<(N + 3) / 4, 256, 0, stream>>>(H, rowptr, srcs, dinv, b0, S, N);
    mfma_gemm<<<ng, 256, 0, stream>>>(S, Wp1, H, N);
    gather_kernel<<<(N + 3) / 4, 256, 0, stream>>>(H, rowptr, srcs, dinv, b1, S, N);
    mfma_gemm<<<ng, 256, 0, stream>>>(S, Wp2, H, N);
    gather_pool_kernel<<<(N + 3) / 4, 256, 0, stream>>>(H, rowptr, srcs, dinv, b2,
                                                        batch, g, N);
    fc_head_kernel<<<NGRAPH, 256, 0, stream>>>(g, fc1W, fc1b, fc2W, fc2b, out);
}

// Round 4
// 375.558 us; speedup vs baseline: 1.1631x; 1.1072x over previous
//
#include <hip/hip_runtime.h>
#include <math.h>

#define FDIM 256
#define NGRAPH 128
#define NCLASS 10

typedef short short8 __attribute__((ext_vector_type(8)));
typedef float floatx4 __attribute__((ext_vector_type(4)));

// fp32 <-> bf16 helpers (RNE)
static __device__ __forceinline__ unsigned short f2bf(float f) {
    unsigned u = __float_as_uint(f);
    u += 0x7FFF + ((u >> 16) & 1);
    return (unsigned short)(u >> 16);
}
static __device__ __forceinline__ float bflo(unsigned u) { return __uint_as_float(u << 16); }
static __device__ __forceinline__ float bfhi(unsigned u) { return __uint_as_float(u & 0xFFFF0000u); }

// ---------------- prep: count+slot | packw x3 | zero g | zero sentinel rows ----------------

__global__ __launch_bounds__(256) void prep_kernel(const int* __restrict__ dst,
                                                   int* __restrict__ cnt,
                                                   unsigned short* __restrict__ slot,
                                                   int E, int nCnt, int N,
                                                   const float* __restrict__ W0,
                                                   const float* __restrict__ W1,
                                                   const float* __restrict__ W2,
                                                   unsigned short* __restrict__ Bp0,
                                                   unsigned short* __restrict__ Bp1,
                                                   unsigned short* __restrict__ Bp2,
                                                   float4* __restrict__ g4,
                                                   unsigned short* __restrict__ Hrow,
                                                   unsigned short* __restrict__ Srow) {
    const int b = blockIdx.x;
    const int t = threadIdx.x;
    if (b < nCnt) {
        int e = b * 256 + t;
        if (e < E) slot[e] = (unsigned short)atomicAdd(&cnt[dst[e]], 1);
        return;
    }
    const int b2 = b - nCnt;
    if (b2 >= 128) {                      // zero sentinel row N of H and S
        Hrow[(size_t)N * FDIM + t] = 0;
        Srow[(size_t)N * FDIM + t] = 0;
        return;
    }
    if (b2 >= 96) {
        g4[(size_t)(b2 - 96) * 256 + t] = (float4){0.f, 0.f, 0.f, 0.f};
        return;
    }
    const float* W = (b2 < 32) ? W0 : (b2 < 64) ? W1 : W2;
    unsigned short* Bp = (b2 < 32) ? Bp0 : (b2 < 64) ? Bp1 : Bp2;
    int idx = (b2 & 31) * 256 + t;   // [0, 8192)
    int kstep = idx >> 10;
    int ntile = (idx >> 6) & 15;
    int lane  = idx & 63;
    int col   = ntile * 16 + (lane & 15);
    int krow  = kstep * 32 + (lane >> 4) * 8;
    unsigned short o[8];
#pragma unroll
    for (int j = 0; j < 8; j++) o[j] = f2bf(W[(size_t)(krow + j) * FDIM + col]);
    *(uint4*)(Bp + (size_t)idx * 8) = *(uint4*)o;
}

// ---------------- CSR scan (two dispatches), segments PADDED to multiple of 8 ----------------
// Pad entries get sentinel src = N (dinv[N]=0 => zero contribution).

__global__ __launch_bounds__(256) void csr_bsum(const int* __restrict__ cnt,
                                                int* __restrict__ bsum, int N) {
    __shared__ int red[256];
    const int t = threadIdx.x;
    const int base = blockIdx.x * 1024 + t * 4;
    int s = 0;
#pragma unroll
    for (int i = 0; i < 4; i++)
        if (base + i < N) s += (cnt[base + i] + 7) & ~7;   // padded counts
    red[t] = s;
    __syncthreads();
    for (int off = 128; off > 0; off >>= 1) {
        if (t < off) red[t] += red[t + off];
        __syncthreads();
    }
    if (t == 0) bsum[blockIdx.x] = red[0];
}

__global__ __launch_bounds__(256) void csr_scan2(const int* __restrict__ cnt,
                                                 const int* __restrict__ bsum,
                                                 int* __restrict__ rowptr,
                                                 float* __restrict__ dinv,
                                                 unsigned short* __restrict__ srcs, int N) {
    __shared__ int redo[256];
    __shared__ int tsum[256];
    const int t = threadIdx.x;
    const int bid = blockIdx.x;

    int pre = 0;
    for (int i = t; i < bid; i += 256) pre += bsum[i];
    redo[t] = pre;
    __syncthreads();
    for (int off = 128; off > 0; off >>= 1) {
        if (t < off) redo[t] += redo[t + off];
        __syncthreads();
    }
    const int blockoff = redo[0];
    __syncthreads();

    const int base = bid * 1024 + t * 4;
    int c[4], pc[4];
    int s = 0;
#pragma unroll
    for (int i = 0; i < 4; i++) {
        c[i] = (base + i < N) ? cnt[base + i] : 0;
        pc[i] = (c[i] + 7) & ~7;                 // padded
        s += pc[i];
    }
    tsum[t] = s;
    __syncthreads();
    for (int off = 1; off < 256; off <<= 1) {
        int v = (t >= off) ? tsum[t - off] : 0;
        __syncthreads();
        tsum[t] += v;
        __syncthreads();
    }
    int run = blockoff + ((t == 0) ? 0 : tsum[t - 1]);
    const unsigned short sent = (unsigned short)N;
#pragma unroll
    for (int i = 0; i < 4; i++) {
        int idx = base + i;
        if (idx < N) {
            rowptr[idx] = run;
            dinv[idx] = rsqrtf((float)c[i] + 1.0f);   // +1 = self loop (real count)
            for (int j = c[i]; j < pc[i]; j++) srcs[run + j] = sent;   // pad entries
            run += pc[i];
            if (idx == N - 1) rowptr[N] = run;        // padded total
        }
    }
    if (bid == 0 && t == 0) dinv[N] = 0.0f;           // sentinel weight
}

// ---------------- GEMM tile body: 64 rows/block, LDS-staged A, register-resident B ----------------
// LDS layout: off_bytes(row, ks, quad) = ks*4096 + row*64 + (quad ^ (ks&3))*16.
// Chunk (row,ks,quad) holds cols [ks*32+quad*8, +8) of row => exactly one MFMA A-fragment.
// Read side: per (mt,ks) the 64 lanes read a permutation of a contiguous 1KB => conflict-free.

template<int AFP32>
static __device__ __forceinline__ void gemm_tile64(const void* __restrict__ A,
                                                   const unsigned short* __restrict__ Bp,
                                                   unsigned short* __restrict__ C,
                                                   int M, int tile,
                                                   unsigned short* __restrict__ As) {
    const int t    = threadIdx.x;
    const int wave = t >> 6;
    const int lane = t & 63;
    const int quad = lane >> 4;
    const int m    = lane & 15;
    const int row0 = tile * 64;

    // B slice preload: wave w owns cols [w*64, w*64+64), 32 x short8 regs
    short8 breg[8][4];
#pragma unroll
    for (int ks = 0; ks < 8; ks++)
#pragma unroll
        for (int j = 0; j < 4; j++)
            breg[ks][j] = *(const short8*)((const short*)Bp +
                            ((size_t)((ks * 16 + wave * 4 + j) * 64 + lane) * 8));

    // stage A tile (64 rows x 256 cols) into LDS; 8 independent chunks per thread
    {
        const int tl   = t & 31;                 // col chunk: cols [tl*8, tl*8+8)
        const int ksw  = tl >> 2;
        const int qw   = (tl & 3) ^ (ksw & 3);
        const int rb   = t >> 5;                 // row base 0..7
        unsigned short* wp = As + ksw * 2048 + qw * 8;   // elem offset
        const int maxe = M * 256 - 8;
#pragma unroll
        for (int k = 0; k < 8; k++) {
            int row = k * 8 + rb;
            int e = tile * 16384 + row * 256 + tl * 8;
            if (e > maxe) e = maxe;              // clamp (garbage rows discarded at store)
            unsigned short ob[8];
            if (AFP32) {
                const float* srcp = (const float*)A + e;
                float4 p0 = *(const float4*)srcp;
                float4 p1 = *(const float4*)(srcp + 4);
                ob[0] = f2bf(p0.x); ob[1] = f2bf(p0.y);
                ob[2] = f2bf(p0.z); ob[3] = f2bf(p0.w);
                ob[4] = f2bf(p1.x); ob[5] = f2bf(p1.y);
                ob[6] = f2bf(p1.z); ob[7] = f2bf(p1.w);
                *(uint4*)(wp + row * 32) = *(uint4*)ob;
            } else {
                *(uint4*)(wp + row * 32) = *(const uint4*)((const unsigned short*)A + e);
            }
        }
    }
    __syncthreads();

#pragma unroll
    for (int mt = 0; mt < 4; mt++) {
        floatx4 acc[4];
#pragma unroll
        for (int j = 0; j < 4; j++) acc[j] = (floatx4){0.f, 0.f, 0.f, 0.f};
#pragma unroll
        for (int ks = 0; ks < 8; ks++) {
            short8 a = *(const short8*)(As + ks * 2048 + (mt * 16 + m) * 32 +
                                        (quad ^ (ks & 3)) * 8);
#pragma unroll
            for (int j = 0; j < 4; j++)
                acc[j] = __builtin_amdgcn_mfma_f32_16x16x32_bf16(a, breg[ks][j], acc[j], 0, 0, 0);
        }
#pragma unroll
        for (int j = 0; j < 4; j++) {
            int col = (wave * 4 + j) * 16 + m;
#pragma unroll
            for (int r = 0; r < 4; r++) {
                int row = row0 + mt * 16 + quad * 4 + r;
                if (row < M) C[(size_t)row * FDIM + col] = f2bf(acc[j][r]);
            }
        }
    }
}

// combo: blocks [0,ng) = gemm0 tiles (fp32 A); blocks [ng, ...) = CSR fill (srcs only)
__global__ __launch_bounds__(256, 2) void gemm0_fill_kernel(const float* __restrict__ x,
                                                            const unsigned short* __restrict__ Bp0,
                                                            unsigned short* __restrict__ H,
                                                            int M, int ng,
                                                            const int* __restrict__ src,
                                                            const int* __restrict__ dst,
                                                            const int* __restrict__ rowptr,
                                                            const unsigned short* __restrict__ slot,
                                                            unsigned short* __restrict__ srcs, int E) {
    __shared__ unsigned short As[16384];   // 32 KB
    if ((int)blockIdx.x < ng) {
        gemm_tile64<1>(x, Bp0, H, M, blockIdx.x, As);
        return;
    }
    int e = (blockIdx.x - ng) * 256 + threadIdx.x;
    if (e < E) srcs[rowptr[dst[e]] + (int)slot[e]] = (unsigned short)src[e];
}

// bf16 GEMM: standalone dispatch
__global__ __launch_bounds__(256, 2) void mfma_gemm(const unsigned short* __restrict__ A,
                                                    const unsigned short* __restrict__ Bp,
                                                    unsigned short* __restrict__ C, int M) {
    __shared__ unsigned short As[16384];   // 32 KB
    gemm_tile64<0>(A, Bp, C, M, blockIdx.x, As);
}

// ---------------- gather core: one node per 64-lane wave ----------------
// Segments padded to x8; pad entries have src=N with dinv[N]=0 and zeroed row N.

static __device__ __forceinline__ void gather_node64(const unsigned short* __restrict__ h,
                                                     const int* __restrict__ rowptr,
                                                     const unsigned short* __restrict__ srcs,
                                                     const float* __restrict__ dinv,
                                                     const float* __restrict__ bias,
                                                     int node, int lane, float* acc) {
    const float di = dinv[node];
    const float dii = di * di;
    uint2 sv = *(const uint2*)(h + (size_t)node * FDIM + lane * 4);
    float4 b = *(const float4*)(bias + lane * 4);
    acc[0] = dii * bflo(sv.x) + b.x;
    acc[1] = dii * bfhi(sv.x) + b.y;
    acc[2] = dii * bflo(sv.y) + b.z;
    acc[3] = dii * bfhi(sv.y) + b.w;

    const int beg = rowptr[node];
    const int end = rowptr[node + 1];
    for (int p = beg; p < end; p += 8) {
        uint4 s8 = *(const uint4*)(srcs + p);          // 8 x u16, wave-uniform
        const unsigned short* sp = (const unsigned short*)&s8;
        int si[8];
        float ds[8];
        uint2 v[8];
#pragma unroll
        for (int i = 0; i < 8; i++) {
            si[i] = __builtin_amdgcn_readfirstlane((int)sp[i]);   // scalarize
            ds[i] = dinv[si[i]];                                   // SMEM path
            v[i] = *(const uint2*)(h + (size_t)si[i] * FDIM + lane * 4);
        }
#pragma unroll
        for (int i = 0; i < 8; i++) {
            float nm = ds[i] * di;
            acc[0] += nm * bflo(v[i].x);
            acc[1] += nm * bfhi(v[i].x);
            acc[2] += nm * bflo(v[i].y);
            acc[3] += nm * bfhi(v[i].y);
        }
    }
#pragma unroll
    for (int i = 0; i < 4; i++) acc[i] = fmaxf(acc[i], 0.0f);
}

__global__ __launch_bounds__(256) void gather_kernel(const unsigned short* __restrict__ h,
                                                     const int* __restrict__ rowptr,
                                                     const unsigned short* __restrict__ srcs,
                                                     const float* __restrict__ dinv,
                                                     const float* __restrict__ bias,
                                                     unsigned short* __restrict__ out, int N) {
    int node = blockIdx.x * 4 + (threadIdx.x >> 6);
    node = __builtin_amdgcn_readfirstlane(node);       // wave-uniform -> scalar loads
    const int lane = threadIdx.x & 63;
    if (node >= N) return;
    float acc[4];
    gather_node64(h, rowptr, srcs, dinv, bias, node, lane, acc);
    unsigned short o[4];
#pragma unroll
    for (int i = 0; i < 4; i++) o[i] = f2bf(acc[i]);
    *(uint2*)(out + (size_t)node * FDIM + lane * 4) = *(uint2*)o;
}

// last layer: gather + pool fused
__global__ __launch_bounds__(256) void gather_pool_kernel(const unsigned short* __restrict__ h,
                                                          const int* __restrict__ rowptr,
                                                          const unsigned short* __restrict__ srcs,
                                                          const float* __restrict__ dinv,
                                                          const float* __restrict__ bias,
                                                          const int* __restrict__ batch,
                                                          float* __restrict__ g, int N) {
    __shared__ float red[4][FDIM];   // 4 KB
    __shared__ int bid[4];
    const int hw   = threadIdx.x >> 6;
    const int lane = threadIdx.x & 63;
    int node = blockIdx.x * 4 + hw;
    node = __builtin_amdgcn_readfirstlane(node);

    float acc[4] = {0.f, 0.f, 0.f, 0.f};
    if (node < N) gather_node64(h, rowptr, srcs, dinv, bias, node, lane, acc);
#pragma unroll
    for (int i = 0; i < 4; i++) red[hw][lane * 4 + i] = acc[i];
    if (lane == 0) bid[hw] = (node < N) ? batch[node] : -1;
    __syncthreads();

    const int f = threadIdx.x;
    int cur = -1;
    float run = 0.0f;
    for (int i = 0; i < 4; i++) {
        int b = bid[i];
        if (b < 0) break;
        if (b != cur) {
            if (cur >= 0) atomicAdd(&g[(size_t)cur * FDIM + f], run);
            cur = b;
            run = 0.0f;
        }
        run += red[i][f];
    }
    if (cur >= 0) atomicAdd(&g[(size_t)cur * FDIM + f], run);
}

// ---------------- fused FC head ----------------

__global__ __launch_bounds__(256) void fc_head_kernel(const float* __restrict__ g,
                                                      const float* __restrict__ fc1W,
                                                      const float* __restrict__ fc1b,
                                                      const float* __restrict__ fc2W,
                                                      const float* __restrict__ fc2b,
                                                      float* __restrict__ out) {
    __shared__ float gs[FDIM];
    __shared__ float part[4][FDIM];
    __shared__ float hs[FDIM];
    __shared__ float p2[256];
    __shared__ float logits[NCLASS];
    const int r = blockIdx.x;
    const int t = threadIdx.x;
    const int w = t >> 6;
    const int l = t & 63;

    gs[t] = g[(size_t)r * FDIM + t];
    __syncthreads();

    float a[4] = {0.f, 0.f, 0.f, 0.f};
    for (int kk = 0; kk < 64; kk++) {
        int k = w * 64 + kk;
        float gv = gs[k];
#pragma unroll
        for (int j = 0; j < 4; j++) a[j] += gv * fc1W[(size_t)k * FDIM + j * 64 + l];
    }
#pragma unroll
    for (int j = 0; j < 4; j++) part[w][j * 64 + l] = a[j];
    __syncthreads();

    float s1 = part[0][t] + part[1][t] + part[2][t] + part[3][t] + fc1b[t];
    hs[t] = fmaxf(s1, 0.0f);
    __syncthreads();

    float a2 = 0.0f;
    const int c = t & 15;
    if (c < NCLASS) {
        int k0 = (t >> 4) * 16;
        for (int kk = 0; kk < 16; kk++)
            a2 += hs[k0 + kk] * fc2W[(size_t)(k0 + kk) * NCLASS + c];
    }
    p2[t] = a2;
    __syncthreads();

    if (t < NCLASS) {
        float s2 = fc2b[t];
        for (int seg = 0; seg < 16; seg++) s2 += p2[seg * 16 + t];
        logits[t] = s2;
    }
    __syncthreads();

    if (t == 0) {
        float mx = logits[0];
        for (int cc = 1; cc < NCLASS; cc++) mx = fmaxf(mx, logits[cc]);
        float ssum = 0.0f;
        for (int cc = 0; cc < NCLASS; cc++) ssum += expf(logits[cc] - mx);
        float lse = mx + logf(ssum);
        for (int cc = 0; cc < NCLASS; cc++) out[(size_t)r * NCLASS + cc] = logits[cc] - lse;
    }
}

// ---------------- launcher ----------------

extern "C" void kernel_launch(void* const* d_in, const int* in_sizes, int n_in,
                              void* d_out, int out_size, void* d_ws, size_t ws_size,
                              hipStream_t stream) {
    const float* x     = (const float*)d_in[0];
    const int*   ei    = (const int*)d_in[1];
    const int*   batch = (const int*)d_in[2];
    const float* W0 = (const float*)d_in[3];  const float* b0 = (const float*)d_in[4];
    const float* W1 = (const float*)d_in[5];  const float* b1 = (const float*)d_in[6];
    const float* W2 = (const float*)d_in[7];  const float* b2 = (const float*)d_in[8];
    const float* fc1W = (const float*)d_in[9];  const float* fc1b = (const float*)d_in[10];
    const float* fc2W = (const float*)d_in[11]; const float* fc2b = (const float*)d_in[12];
    float* out = (float*)d_out;

    const int N = in_sizes[0] / FDIM;
    const int E = in_sizes[1] / 2;
    const int* src = ei;
    const int* dst = ei + E;
    const int Mpad = ((N + 63) / 64) * 64;
    const int nb   = (N + 1023) / 1024;
    const int nCnt = (E + 255) / 256;
    const int ng   = (N + 63) / 64;              // 64 rows per block
    const size_t Epad = (size_t)E + 8 * (size_t)N;   // upper bound on padded CSR length

    // workspace layout (16B-aligned chunks); +1 row on S/H for sentinel node N
    char* p = (char*)d_ws;
    unsigned short* S  = (unsigned short*)p; p += (size_t)(Mpad + 64) * FDIM * 2;  // node state
    unsigned short* H  = (unsigned short*)p; p += (size_t)(Mpad + 64) * FDIM * 2;  // GEMM out
    unsigned short* Wp0 = (unsigned short*)p; p += (size_t)8192 * 8 * 2;
    unsigned short* Wp1 = (unsigned short*)p; p += (size_t)8192 * 8 * 2;
    unsigned short* Wp2 = (unsigned short*)p; p += (size_t)8192 * 8 * 2;
    float* dinv = (float*)p; p += (((size_t)(N + 1) * 4 + 15) & ~15ull);
    int*   cnt  = (int*)p;   p += (size_t)N * 4;
    int*   rowptr = (int*)p; p += (size_t)(N + 4) * 4;
    int*   bsum = (int*)p;   p += (size_t)256 * 4;
    unsigned short* srcs = (unsigned short*)p; p += ((Epad * 2 + 15) & ~15ull);
    unsigned short* slot = (unsigned short*)p; p += (((size_t)E * 2 + 15) & ~15ull);
    float* g    = (float*)p;

    // ---- CSR build + weight pack ----
    hipMemsetAsync(cnt, 0, (size_t)N * sizeof(int), stream);
    prep_kernel<<<nCnt + 129, 256, 0, stream>>>(dst, cnt, slot, E, nCnt, N,
                                                W0, W1, W2, Wp0, Wp1, Wp2, (float4*)g, H, S);
    csr_bsum<<<nb, 256, 0, stream>>>(cnt, bsum, N);
    csr_scan2<<<nb, 256, 0, stream>>>(cnt, bsum, rowptr, dinv, srcs, N);

    // ---- gemm0 (x@W0 -> H) + fill (srcs), one dispatch ----
    gemm0_fill_kernel<<<ng + nCnt, 256, 0, stream>>>(x, Wp0, H, N, ng,
                                                     src, dst, rowptr, slot, srcs, E);

    // ---- layers ----
    gather_kernel<<<(N + 3) / 4, 256, 0, stream>>>(H, rowptr, srcs, dinv, b0, S, N);
    mfma_gemm<<<ng, 256, 0, stream>>>(S, Wp1, H, N);
    gather_kernel<<<(N + 3) / 4, 256, 0, stream>>>(H, rowptr, srcs, dinv, b1, S, N);
    mfma_gemm<<<ng, 256, 0, stream>>>(S, Wp2, H, N);
    gather_pool_kernel<<<(N + 3) / 4, 256, 0, stream>>>(H, rowptr, srcs, dinv, b2,
                                                        batch, g, N);
    fc_head_kernel<<<NGRAPH, 256, 0, stream>>>(g, fc1W, fc1b, fc2W, fc2b, out);
}